// Round 2
// baseline (77.153 us; speedup 1.0000x reference)
//
#include <hip/hip_runtime.h>
#include <math.h>

// Problem constants (fixed by setup_inputs in the reference)
#define HH   512
#define NST  32
#define MM   2
#define LL   2048
#define NS   (MM * NST)   // 64 fractional states per h
#define NT   128          // threads per block
#define TL   16           // l per thread; 128 threads * 16 = 2048 = L

// K[h,l] = 2*Re( sum_s C_disc[h,s] * w_s^l ),  w = exp(dtA)
//
// r_s(l) = Re(Cc_s * w_s^l) obeys the exactly-stable 2nd-order recurrence
//   r(l+1) = p*r(l) + q*r(l-1),  p = 2*Re(w), q = -|w|^2
// -> 3 VALU slots per (state,l) and ZERO transcendentals in the main loop.
// Chunk-start values come from factored LDS power tables:
//   l0 = 16*tid, tid = 8*qi + ri  =>  w^l0 = (w^128)^qi * (w^16)^ri
//   T1[s][ri] = {Re,Im(w^(16ri)), Re,Im(w^(16ri+1))}   (8 entries)
//   T2[s][qi] = {Re,Im(Cc*(w^128)^qi), p, q}           (16 entries)
//
// v2 -> v3: TL 8 -> 16 with 128 threads. The main loop was LDS-issue-bound
// (2 ds_read_b128 per state per thread; ~1024 b128/CU vs ~2.6us of VALU).
// Doubling l-per-thread halves the LDS instruction count at equal VALU,
// bringing the two pipes to parity (~2.6us each). Tables stay XOR-swizzled
// (conflict-free writes and reads), build is 2-way wave-parallel, and the
// 4-state group loads stay ping-pong double-buffered (1 wave/SIMD resident,
// so ILP must cover the ~120cy LDS latency; ~384cy of FMA per group does).
__global__ __launch_bounds__(NT) void loong_kernel(
    const float* __restrict__ C_real,      // [1, H, NST, 2]
    const float* __restrict__ log_dt,      // [H]
    const float* __restrict__ log_A_real,  // [H, NST]
    const float* __restrict__ A_imag,      // [H, NST]
    const float* __restrict__ omega_logit, // [M]
    const float* __restrict__ eta_logit,   // [M]
    float* __restrict__ out)               // [1, H, L]
{
    __shared__ float4 sT1[NS][8];    //  8 KB
    __shared__ float4 sT2[NS][16];   // 16 KB

    const int h   = blockIdx.x;
    const int tid = threadIdx.x;

    // ---- Preamble: 128 threads, 2 per state (part = wave index) ----
    {
        const int s    = tid & (NS - 1);
        const int part = tid >> 6;          // 0..1, wave-uniform
        const int m = s >> 5;
        const int n = s & 31;
        const float dt  = expf(log_dt[h]);
        const float Are = -expf(log_A_real[h * NST + n]);
        const float Aim = A_imag[h * NST + n];
        const float om = 1e-6f + (100.0f - 1e-6f) / (1.0f + expf(-omega_logit[m]));
        const float et = 1e-6f + (10.0f  - 1e-6f) / (1.0f + expf(-eta_logit[m]));
        const float Afr = fmaf(et, Are, -om);
        const float Afi = et * Aim;
        const float Cfr = et * C_real[(h * NST + n) * 2 + 0];
        const float Cfi = et * C_real[(h * NST + n) * 2 + 1];
        const float ar = dt * Afr, ai = dt * Afi;       // dtA
        const float e = expf(ar);
        float sn, cs;
        sincosf(ai, &sn, &cs);                          // |ai| <= ~10, accurate
        const float Er = e * cs, Ei = e * sn;           // w = exp(dtA)
        // C_disc = C_frac * (exp(dtA)-1) / (A_frac + 1e-8)
        const float dr = Afr + 1e-8f, di = Afi;
        const float inv = 1.0f / fmaf(dr, dr, di * di);
        const float numr = Er - 1.0f, numi = Ei;
        const float fr = fmaf(numr, dr,  numi * di) * inv;
        const float fi = fmaf(numi, dr, -numr * di) * inv;
        float Cdr = fmaf(Cfr, fr, -(Cfi * fi));
        float Cdi = fmaf(Cfr, fi,  (Cfi * fr));
        if (sqrtf(fmaf(Afr, Afr, Afi * Afi)) < 1e-6f) { // small-|A| branch
            Cdr = Cfr * dt;
            Cdi = Cfi * dt;
        }
        const float Ccr = 2.0f * Cdr, Cci = 2.0f * Cdi; // fold the 2*Re factor
        const float p  = 2.0f * Er;
        const float qc = -fmaf(Er, Er, Ei * Ei);

        // powers of w by repeated squaring
        const float w2r = fmaf(Er, Er, -(Ei * Ei)),     w2i = 2.0f * Er * Ei;
        const float w4r = fmaf(w2r, w2r, -(w2i * w2i)), w4i = 2.0f * w2r * w2i;
        const float w8r = fmaf(w4r, w4r, -(w4i * w4i)), w8i = 2.0f * w4r * w4i;
        const float w16r  = fmaf(w8r,  w8r,  -(w8i  * w8i)),  w16i  = 2.0f * w8r  * w8i;
        const float w32r  = fmaf(w16r, w16r, -(w16i * w16i)), w32i  = 2.0f * w16r * w16i;
        const float w64r  = fmaf(w32r, w32r, -(w32i * w32i)), w64i  = 2.0f * w32r * w32i;
        const float w128r = fmaf(w64r, w64r, -(w64i * w64i)), w128i = 2.0f * w64r * w64i;

        if (part == 0) {
            // T1: u = (w^16)^r, plus u*w, for r = 0..7
            float ur = 1.0f, ui = 0.0f;
#pragma unroll
            for (int r = 0; r < 8; ++r) {
                sT1[s][r ^ (s & 7)] = make_float4(ur, ui,
                                                  fmaf(ur, Er, -(ui * Ei)),
                                                  fmaf(ur, Ei,  (ui * Er)));
                const float nr = fmaf(ur, w16r, -(ui * w16i));
                const float ni = fmaf(ur, w16i,  (ui * w16r));
                ur = nr; ui = ni;
            }
            // T2 low half: v = Cc*(w^128)^e, e = 0..7
            float vr = Ccr, vi = Cci;
#pragma unroll
            for (int q = 0; q < 8; ++q) {
                sT2[s][q ^ (s & 15)] = make_float4(vr, vi, p, qc);
                const float nr = fmaf(vr, w128r, -(vi * w128i));
                const float ni = fmaf(vr, w128i,  (vi * w128r));
                vr = nr; vi = ni;
            }
        } else {
            // T2 high half: jump in at Cc*w^1024, e = 8..15
            const float w256r  = fmaf(w128r, w128r, -(w128i * w128i)), w256i  = 2.0f * w128r * w128i;
            const float w512r  = fmaf(w256r, w256r, -(w256i * w256i)), w512i  = 2.0f * w256r * w256i;
            const float w1024r = fmaf(w512r, w512r, -(w512i * w512i)), w1024i = 2.0f * w512r * w512i;
            float vr = fmaf(Ccr, w1024r, -(Cci * w1024i));
            float vi = fmaf(Ccr, w1024i,  (Cci * w1024r));
#pragma unroll
            for (int q = 8; q < 16; ++q) {
                sT2[s][q ^ (s & 15)] = make_float4(vr, vi, p, qc);
                const float nr = fmaf(vr, w128r, -(vi * w128i));
                const float ni = fmaf(vr, w128i,  (vi * w128r));
                vr = nr; vi = ni;
            }
        }
    }
    __syncthreads();

    const int ri = tid & 7;
    const int qi = tid >> 3;

    float acc[TL];
#pragma unroll
    for (int j = 0; j < TL; ++j) acc[j] = 0.0f;

    float4 A1[4], A2[4], B1[4], B2[4];

#define LOADG(T1v, T2v, S0)                                            \
    _Pragma("unroll")                                                  \
    for (int u = 0; u < 4; ++u) {                                      \
        const int ss = (S0) + u;                                       \
        T1v[u] = sT1[ss][ri ^ (ss & 7)];                               \
        T2v[u] = sT2[ss][qi ^ (ss & 15)];                              \
    }

#define COMPG(T1v, T2v)                                                \
    _Pragma("unroll")                                                  \
    for (int u = 0; u < 4; ++u) {                                      \
        const float pp = T2v[u].z, qq = T2v[u].w;                      \
        float r0 = fmaf(T1v[u].x, T2v[u].x, -(T1v[u].y * T2v[u].y));   \
        float r1 = fmaf(T1v[u].z, T2v[u].x, -(T1v[u].w * T2v[u].y));   \
        acc[0] += r0;                                                  \
        acc[1] += r1;                                                  \
        _Pragma("unroll")                                              \
        for (int j = 2; j < TL; ++j) {                                 \
            const float rn = fmaf(pp, r1, qq * r0);                    \
            acc[j] += rn;                                              \
            r0 = r1; r1 = rn;                                          \
        }                                                              \
    }

    // ping-pong pipeline over 16 groups of 4 states: load one group ahead
    LOADG(A1, A2, 0)
#pragma unroll
    for (int g = 0; g < 7; ++g) {
        LOADG(B1, B2, 8 * g + 4)
        COMPG(A1, A2)
        LOADG(A1, A2, 8 * g + 8)
        COMPG(B1, B2)
    }
    LOADG(B1, B2, 60)
    COMPG(A1, A2)
    COMPG(B1, B2)

#undef LOADG
#undef COMPG

    float4* o = reinterpret_cast<float4*>(out + (size_t)h * LL + (size_t)tid * TL);
    o[0] = make_float4(acc[0],  acc[1],  acc[2],  acc[3]);
    o[1] = make_float4(acc[4],  acc[5],  acc[6],  acc[7]);
    o[2] = make_float4(acc[8],  acc[9],  acc[10], acc[11]);
    o[3] = make_float4(acc[12], acc[13], acc[14], acc[15]);
}

extern "C" void kernel_launch(void* const* d_in, const int* in_sizes, int n_in,
                              void* d_out, int out_size, void* d_ws, size_t ws_size,
                              hipStream_t stream) {
    const float* C_real      = (const float*)d_in[0];
    const float* log_dt      = (const float*)d_in[1];
    const float* log_A_real  = (const float*)d_in[2];
    const float* A_imag      = (const float*)d_in[3];
    const float* omega_logit = (const float*)d_in[4];
    const float* eta_logit   = (const float*)d_in[5];
    float* out = (float*)d_out;

    loong_kernel<<<dim3(HH), dim3(NT), 0, stream>>>(
        C_real, log_dt, log_A_real, A_imag, omega_logit, eta_logit, out);
}

// Round 3
// 72.982 us; speedup vs baseline: 1.0572x; 1.0572x over previous
//
#include <hip/hip_runtime.h>
#include <math.h>

// Problem constants (fixed by setup_inputs in the reference)
#define HH   512
#define NST  32
#define MM   2
#define LL   2048
#define NS   (MM * NST)   // 64 fractional states per h
#define NT   256

// K[h,l] = 2*Re( sum_s C_disc[h,s] * w_s^l ),  w = exp(dtA)
//
// r_s(l) = Re(Cc_s * w_s^l) obeys the exactly-stable 2nd-order recurrence
//   r(l+1) = p*r(l) + q*r(l-1),  p = 2*Re(w), q = -|w|^2.
//
// v3 -> v4 (wave-owns-states): the old per-thread (ri,qi) factorization
// forced 2 ds_read_b128 per (wave,state) = 1024 b128/CU ~ 5.1us, LDS-bound.
// Now wave w owns states [16w,16w+16) and lane L covers l = 32L..32L+31
// (acc[32] in regs, whole L per wave). Seeds: z = Cc * (w^32)^L ->
//   * T1z[s][L] = (w^32)^L : one b64 spread read/state (XOR-swizzled, free)
//   * U[s] = {Ccr,Cci,wr,wi}: one b128 wave-uniform broadcast read/state
// => 2 LDS reads per (wave,STATE-of-16) = 256 reads/CU ~ 1us; p,q recomputed
// from w in 3 VALU. Occupancy stays 8 waves/CU = 2/SIMD (round-2 lesson:
// 1 wave/SIMD exposes all latency). Cross-wave reduction of the 4 partial
// K vectors goes through LDS (aliases T1z after a barrier) and produces
// fully-coalesced float4 stores.
__global__ __launch_bounds__(NT) void loong_kernel(
    const float* __restrict__ C_real,      // [1, H, NST, 2]
    const float* __restrict__ log_dt,      // [H]
    const float* __restrict__ log_A_real,  // [H, NST]
    const float* __restrict__ A_imag,      // [H, NST]
    const float* __restrict__ omega_logit, // [M]
    const float* __restrict__ eta_logit,   // [M]
    float* __restrict__ out)               // [1, H, L]
{
    // 8192 floats (T1z as [64][64] float2, XOR-swizzled cols) + 256 floats (U)
    // sR ([4][512] float4 = 8192 floats) aliases T1z after the main loop.
    __shared__ __align__(16) float sbuf[64 * 64 * 2 + 64 * 4];
    float2* T1z = reinterpret_cast<float2*>(sbuf);          // [64][64]
    float4* U   = reinterpret_cast<float4*>(sbuf + 8192);   // [64]
    float4* sR  = reinterpret_cast<float4*>(sbuf);          // [4][512]

    const int h   = blockIdx.x;
    const int tid = threadIdx.x;
    const int wv  = tid >> 6;        // wave id, 0..3 (wave-uniform)
    const int ln  = tid & 63;        // lane id

    // ---- Preamble: 4 waves x 64 lanes; lane=state, wave=quarter of T1z ----
    {
        const int s    = ln;
        const int part = wv;                      // wave-uniform
        const int m = s >> 5;
        const int n = s & 31;
        const float dt  = expf(log_dt[h]);
        const float Are = -expf(log_A_real[h * NST + n]);
        const float Aim = A_imag[h * NST + n];
        const float om = 1e-6f + (100.0f - 1e-6f) / (1.0f + expf(-omega_logit[m]));
        const float et = 1e-6f + (10.0f  - 1e-6f) / (1.0f + expf(-eta_logit[m]));
        const float Afr = fmaf(et, Are, -om);
        const float Afi = et * Aim;
        const float Cfr = et * C_real[(h * NST + n) * 2 + 0];
        const float Cfi = et * C_real[(h * NST + n) * 2 + 1];
        const float ar = dt * Afr, ai = dt * Afi;       // dtA
        const float e = expf(ar);
        float sn, cs;
        sincosf(ai, &sn, &cs);                          // |ai| <= ~10, accurate
        const float Er = e * cs, Ei = e * sn;           // w = exp(dtA)
        // C_disc = C_frac * (exp(dtA)-1) / (A_frac + 1e-8)
        const float dr = Afr + 1e-8f, di = Afi;
        const float inv = 1.0f / fmaf(dr, dr, di * di);
        const float numr = Er - 1.0f, numi = Ei;
        const float fr = fmaf(numr, dr,  numi * di) * inv;
        const float fi = fmaf(numi, dr, -numr * di) * inv;
        float Cdr = fmaf(Cfr, fr, -(Cfi * fi));
        float Cdi = fmaf(Cfr, fi,  (Cfi * fr));
        if (sqrtf(fmaf(Afr, Afr, Afi * Afi)) < 1e-6f) { // small-|A| branch
            Cdr = Cfr * dt;
            Cdi = Cfi * dt;
        }
        const float Ccr = 2.0f * Cdr, Cci = 2.0f * Cdi; // fold the 2*Re factor

        // w^32 via 5 complex squarings
        float xr = Er, xi = Ei;
#pragma unroll
        for (int k = 0; k < 5; ++k) {
            const float nr = fmaf(xr, xr, -(xi * xi));
            const float ni = 2.0f * xr * xi;
            xr = nr; xi = ni;
        }
        const float w32r = xr, w32i = xi;
        // (w^32)^16, ^32, ^48 for the per-wave jump-in
        float yr = w32r, yi = w32i;
#pragma unroll
        for (int k = 0; k < 4; ++k) {
            const float nr = fmaf(yr, yr, -(yi * yi));
            const float ni = 2.0f * yr * yi;
            yr = nr; yi = ni;
        }
        const float t16r = yr, t16i = yi;
        const float t32r = fmaf(t16r, t16r, -(t16i * t16i));
        const float t32i = 2.0f * t16r * t16i;
        const float t48r = fmaf(t32r, t16r, -(t32i * t16i));
        const float t48i = fmaf(t32r, t16i,  (t32i * t16r));

        float cr = 1.0f, ci = 0.0f;
        if      (part == 1) { cr = t16r; ci = t16i; }
        else if (part == 2) { cr = t32r; ci = t32i; }
        else if (part == 3) { cr = t48r; ci = t48i; }

        // chain: entries L = 16*part + k, value (w^32)^L, col XOR-swizzled
#pragma unroll
        for (int k = 0; k < 16; ++k) {
            const int col = (16 * part + k) ^ s;
            T1z[s * 64 + col] = make_float2(cr, ci);
            const float nr = fmaf(cr, w32r, -(ci * w32i));
            const float ni = fmaf(cr, w32i,  (ci * w32r));
            cr = nr; ci = ni;
        }
        if (part == 0) U[s] = make_float4(Ccr, Cci, Er, Ei);
    }
    __syncthreads();

    // ---- Main loop: wave wv handles states [16wv, 16wv+16), lane ln
    //      covers l = 32*ln .. 32*ln+31 via the 2nd-order recurrence ----
    float acc[32];
#pragma unroll
    for (int j = 0; j < 32; ++j) acc[j] = 0.0f;

    const int sb = wv << 4;

#define STATE_COMP(u, Uv)                                              \
    {                                                                  \
        const float zr = fmaf((u).x, (Uv).x, -((u).y * (Uv).y));       \
        const float zi = fmaf((u).x, (Uv).y,  ((u).y * (Uv).x));       \
        const float wr = (Uv).z, wi = (Uv).w;                          \
        const float p  = wr + wr;                                      \
        const float qn = fmaf(wr, wr, wi * wi);                        \
        float r0 = zr;                                                 \
        float r1 = fmaf(zr, wr, -(zi * wi));                           \
        acc[0] += r0;                                                  \
        acc[1] += r1;                                                  \
        _Pragma("unroll")                                              \
        for (int j = 2; j < 32; ++j) {                                 \
            const float t  = qn * r0;                                  \
            const float rn = fmaf(p, r1, -t);                          \
            acc[j] += rn;                                              \
            r0 = r1; r1 = rn;                                          \
        }                                                              \
    }

    // ping-pong prefetch over 8 state-pairs
    float2 uA = T1z[(sb + 0) * 64 + (ln ^ (sb + 0))];
    float4 UA = U[sb + 0];
    float2 uB = T1z[(sb + 1) * 64 + (ln ^ (sb + 1))];
    float4 UB = U[sb + 1];
#pragma unroll
    for (int i = 0; i < 8; ++i) {
        float2 nuA = uA, nuB = uB;
        float4 nUA = UA, nUB = UB;
        if (i < 7) {
            const int sA = sb + 2 * i + 2, sBt = sA + 1;
            nuA = T1z[sA * 64 + (ln ^ sA)];
            nUA = U[sA];
            nuB = T1z[sBt * 64 + (ln ^ sBt)];
            nUB = U[sBt];
        }
        STATE_COMP(uA, UA)
        STATE_COMP(uB, UB)
        uA = nuA; UA = nUA; uB = nuB; UB = nUB;
    }
#undef STATE_COMP

    // ---- Cross-wave reduction through LDS (sR aliases T1z) ----
    __syncthreads();
    {
        float4* sRw = sR + wv * 512;
#pragma unroll
        for (int c = 0; c < 8; ++c) {
            const int scol = 8 * ln + (c ^ (ln & 7));
            sRw[scol] = make_float4(acc[4 * c + 0], acc[4 * c + 1],
                                    acc[4 * c + 2], acc[4 * c + 3]);
        }
    }
    __syncthreads();
    {
        float4* op = reinterpret_cast<float4*>(out + (size_t)h * LL);
#pragma unroll
        for (int k = 0; k < 2; ++k) {
            const int col  = (wv << 7) + (k << 6) + ln;   // [0,512)
            const int scol = (col & ~7) | ((col & 7) ^ ((col >> 3) & 7));
            const float4 a = sR[scol];
            const float4 b = sR[512 + scol];
            const float4 c4 = sR[1024 + scol];
            const float4 d = sR[1536 + scol];
            float4 sm;
            sm.x = (a.x + b.x) + (c4.x + d.x);
            sm.y = (a.y + b.y) + (c4.y + d.y);
            sm.z = (a.z + b.z) + (c4.z + d.z);
            sm.w = (a.w + b.w) + (c4.w + d.w);
            op[col] = sm;                                  // fully coalesced
        }
    }
}

extern "C" void kernel_launch(void* const* d_in, const int* in_sizes, int n_in,
                              void* d_out, int out_size, void* d_ws, size_t ws_size,
                              hipStream_t stream) {
    const float* C_real      = (const float*)d_in[0];
    const float* log_dt      = (const float*)d_in[1];
    const float* log_A_real  = (const float*)d_in[2];
    const float* A_imag      = (const float*)d_in[3];
    const float* omega_logit = (const float*)d_in[4];
    const float* eta_logit   = (const float*)d_in[5];
    float* out = (float*)d_out;

    loong_kernel<<<dim3(HH), dim3(NT), 0, stream>>>(
        C_real, log_dt, log_A_real, A_imag, omega_logit, eta_logit, out);
}